// Round 2
// baseline (356.550 us; speedup 1.0000x reference)
//
#include <hip/hip_runtime.h>
#include <hip/hip_bf16.h>

// EnhancedCondConv2d: B=32, CI=128, CO=256, H=W=64, E=8, R=16, K=3
// Pipeline:
//   k_stats     : per-(b,ci) plane sums -> pooled[b,ci], S_r[b][9][128] (shifted means), zero page
//   k_transpose : x (NCHW f32) -> x_t (NHWC bf16)           [im2col becomes contiguous]
//   k_route     : SE gate -> softmax -> r[b,8]
//   k_combine   : w_r[b][co][kidx][ci] = sum_e r[b,e]*experts  (bf16)
//   k_pout      : p[b,co] = w_r . S_r   (exact pooled conv output, by linearity)
//   k_catt      : ca[b,co] = sigmoid(relu(p@aw1^T)@aw2^T)
//   k_conv      : implicit-GEMM MFMA conv (128x128 tile, 16x16x32 bf16), epilogue *ca

#define BB 32
#define CI_ 128
#define CO_ 256
#define HW_ 4096
#define KK 1152   // CI*9

typedef unsigned short u16;
typedef __attribute__((ext_vector_type(8))) __bf16 bf16x8;
typedef __attribute__((ext_vector_type(4))) float floatx4;

typedef const __attribute__((address_space(1))) void* gptr_t;
typedef __attribute__((address_space(3))) void* sptr_t;

__device__ __forceinline__ void gload_lds16(const void* g, void* s) {
  __builtin_amdgcn_global_load_lds((gptr_t)g, (sptr_t)s, 16, 0, 0);
}

// ---------------- k_stats: per-(b,ci) plane statistics ----------------
__global__ __launch_bounds__(256) void k_stats(const float* __restrict__ x,
                                               float* __restrict__ Sr,
                                               float* __restrict__ pooled,
                                               unsigned* __restrict__ zp) {
  int blk = blockIdx.x;
  if (blk == 0 && threadIdx.x < 64) zp[threadIdx.x] = 0u;  // 256B zero page
  int b = blk >> 7, ci = blk & 127;
  const float4* xp = (const float4*)(x + ((size_t)(b * CI_ + ci) << 12));
  float T = 0.f, r0 = 0.f, r63 = 0.f, c0 = 0.f, c63 = 0.f;
  __shared__ float corn[4];
  __shared__ float wsum[4][5];
  int tid = threadIdx.x;
  for (int k = 0; k < 4; k++) {
    int i4 = tid + (k << 8);
    float4 v = xp[i4];
    float vv[4] = {v.x, v.y, v.z, v.w};
#pragma unroll
    for (int c = 0; c < 4; c++) {
      int e = (i4 << 2) + c;
      int y = e >> 6, xx = e & 63;
      float val = vv[c];
      T += val;
      if (y == 0) r0 += val;
      if (y == 63) r63 += val;
      if (xx == 0) c0 += val;
      if (xx == 63) c63 += val;
      if (e == 0)    corn[0] = val;  // [0][0]
      if (e == 63)   corn[1] = val;  // [0][63]
      if (e == 4032) corn[2] = val;  // [63][0]
      if (e == 4095) corn[3] = val;  // [63][63]
    }
  }
  for (int off = 32; off; off >>= 1) {
    T   += __shfl_down(T, off);
    r0  += __shfl_down(r0, off);
    r63 += __shfl_down(r63, off);
    c0  += __shfl_down(c0, off);
    c63 += __shfl_down(c63, off);
  }
  int w = tid >> 6, lane = tid & 63;
  if (lane == 0) { wsum[w][0]=T; wsum[w][1]=r0; wsum[w][2]=r63; wsum[w][3]=c0; wsum[w][4]=c63; }
  __syncthreads();
  if (tid == 0) {
    T   = wsum[0][0]+wsum[1][0]+wsum[2][0]+wsum[3][0];
    r0  = wsum[0][1]+wsum[1][1]+wsum[2][1]+wsum[3][1];
    r63 = wsum[0][2]+wsum[1][2]+wsum[2][2]+wsum[3][2];
    c0  = wsum[0][3]+wsum[1][3]+wsum[2][3]+wsum[3][3];
    c63 = wsum[0][4]+wsum[1][4]+wsum[2][4]+wsum[3][4];
    pooled[b * CI_ + ci] = T * (1.0f / 4096.0f);
#pragma unroll
    for (int ky = 0; ky < 3; ky++) {
#pragma unroll
      for (int kx = 0; kx < 3; kx++) {
        int dy = ky - 1, dx = kx - 1;
        float s = T;
        if (dy == -1) s -= r63;
        if (dy ==  1) s -= r0;
        if (dx == -1) s -= c63;
        if (dx ==  1) s -= c0;
        if (dy != 0 && dx != 0) s += corn[(dy == -1 ? 2 : 0) + (dx == -1 ? 1 : 0)];
        Sr[(b * 9 + ky * 3 + kx) * CI_ + ci] = s * (1.0f / 4096.0f);
      }
    }
  }
}

// ---------------- k_transpose: NCHW f32 -> NHWC bf16 ----------------
__global__ __launch_bounds__(256) void k_transpose(const float* __restrict__ x,
                                                   u16* __restrict__ xt) {
  int blk = blockIdx.x;          // b*64 + y
  int b = blk >> 6, y = blk & 63;
  __shared__ u16 ts[64][130];    // +2 pad breaks bank conflicts
  int tid = threadIdx.x;
  const float* xb = x + ((size_t)b << 19) + (y << 6);
  for (int k = 0; k < 32; k++) {
    int i = tid + (k << 8);
    int ci = i >> 6, xx = i & 63;
    float v = xb[(size_t)ci * 4096 + xx];
    __hip_bfloat16 h = __float2bfloat16(v);
    ts[xx][ci] = *(const u16*)&h;
  }
  __syncthreads();
  uint2* ot = (uint2*)(xt + ((size_t)b * HW_ + y * 64) * CI_);
  // 64 pixels * 128 u16 = 8192 u16 = 2048 uint2 -> 8 iterations of 256 threads
  // (was k<16 in R1: wrote 2x the region, OOB-read ts[64..127] and clobbered
  //  the next row's xt -> absmax ~3.2)
  for (int k = 0; k < 8; k++) {
    int j = tid + (k << 8);      // [0,2048) uint2s = 8192 u16s
    int pix = j >> 5, cq = (j & 31) << 2;
    uint2 val;
    u16* pv = (u16*)&val;
    pv[0] = ts[pix][cq]; pv[1] = ts[pix][cq + 1];
    pv[2] = ts[pix][cq + 2]; pv[3] = ts[pix][cq + 3];
    ot[j] = val;
  }
}

// ---------------- k_route: SE gate -> softmax over experts ----------------
__global__ __launch_bounds__(128) void k_route(const float* __restrict__ pooled,
    const float* __restrict__ rw1, const float* __restrict__ rb1,
    const float* __restrict__ rw2, const float* __restrict__ rb2,
    const float* __restrict__ rw3, const float* __restrict__ rb3,
    float* __restrict__ r) {
  int b = blockIdx.x, tid = threadIdx.x;
  __shared__ float ps[128], hs[8], ss[128], lg[8];
  ps[tid] = pooled[b * 128 + tid];
  __syncthreads();
  if (tid < 8) {
    float a = rb1[tid];
    for (int c = 0; c < 128; c++) a += ps[c] * rw1[tid * 128 + c];
    hs[tid] = fmaxf(a, 0.f);
  }
  __syncthreads();
  {
    float a = rb2[tid];
    for (int j = 0; j < 8; j++) a += hs[j] * rw2[tid * 8 + j];
    ss[tid] = 1.f / (1.f + expf(-a));
  }
  __syncthreads();
  if (tid < 8) {
    float a = rb3[tid];
    for (int c = 0; c < 128; c++) a += ss[c] * rw3[tid * 128 + c];
    lg[tid] = a;
  }
  __syncthreads();
  if (tid == 0) {
    float m = lg[0];
    for (int e = 1; e < 8; e++) m = fmaxf(m, lg[e]);
    float s = 0.f, ex[8];
    for (int e = 0; e < 8; e++) { ex[e] = expf(lg[e] - m); s += ex[e]; }
    for (int e = 0; e < 8; e++) r[b * 8 + e] = ex[e] / s;
  }
}

// ---------------- k_combine: w_r[b][co][kidx][ci] bf16 ----------------
__global__ __launch_bounds__(128) void k_combine(const float* __restrict__ experts,
                                                 const float* __restrict__ r,
                                                 __hip_bfloat16* __restrict__ wr) {
  int blk = blockIdx.x;          // co*32 + b (same-co blocks adjacent -> L2 reuse of experts)
  int co = blk >> 5, b = blk & 31;
  int ci = threadIdx.x;
  __shared__ float rs[8];
  if (ci < 8) rs[ci] = r[b * 8 + ci];
  __syncthreads();
  float acc[9] = {0.f, 0.f, 0.f, 0.f, 0.f, 0.f, 0.f, 0.f, 0.f};
  for (int e = 0; e < 8; e++) {
    const float* ep = experts + (((size_t)e * 256 + co) * 128 + ci) * 9;
    float wv = rs[e];
#pragma unroll
    for (int k = 0; k < 9; k++) acc[k] += wv * ep[k];
  }
  __hip_bfloat16* wrow = wr + (size_t)(b * 256 + co) * KK;
#pragma unroll
  for (int k = 0; k < 9; k++) wrow[k * 128 + ci] = __float2bfloat16(acc[k]);
}

// ---------------- k_pout: exact pooled conv output p[b,co] ----------------
__global__ __launch_bounds__(64) void k_pout(const __hip_bfloat16* __restrict__ wr,
                                             const float* __restrict__ Sr,
                                             float* __restrict__ p) {
  int blk = blockIdx.x;
  int b = blk >> 8, co = blk & 255;
  int t = threadIdx.x;
  const __hip_bfloat16* wrow = wr + (size_t)(b * 256 + co) * KK;
  const float* sb = Sr + b * KK;
  float a = 0.f;
  for (int i = t; i < KK; i += 64) a += __bfloat162float(wrow[i]) * sb[i];
  for (int off = 32; off; off >>= 1) a += __shfl_down(a, off);
  if (t == 0) p[b * 256 + co] = a;
}

// ---------------- k_catt: channel attention ----------------
__global__ __launch_bounds__(256) void k_catt(const float* __restrict__ p,
    const float* __restrict__ aw1, const float* __restrict__ ab1,
    const float* __restrict__ aw2, const float* __restrict__ ab2,
    float* __restrict__ ca) {
  int b = blockIdx.x, tid = threadIdx.x;
  __shared__ float ps[256], ts[16];
  ps[tid] = p[b * 256 + tid];
  __syncthreads();
  if (tid < 16) {
    float a = ab1[tid];
    for (int c = 0; c < 256; c++) a += ps[c] * aw1[tid * 256 + c];
    ts[tid] = fmaxf(a, 0.f);
  }
  __syncthreads();
  float a = ab2[tid];
  for (int j = 0; j < 16; j++) a += ts[j] * aw2[tid * 16 + j];
  ca[b * 256 + tid] = 1.f / (1.f + expf(-a));
}

// ---------------- k_conv: implicit-GEMM MFMA conv + ca epilogue ----------------
// grid = 32 b * 2 coTile * 32 rowPair; block = 256 (4 waves, 2x2 wave grid)
// Block tile: M=128 co, N=128 pos (2 image rows), K-loop: 9 kidx * 4 ci-blocks of 32.
__global__ __launch_bounds__(256) void k_conv(const u16* __restrict__ xt,
                                              const u16* __restrict__ wr,
                                              const float* __restrict__ ca,
                                              const u16* __restrict__ zp,
                                              float* __restrict__ out) {
  int blk = blockIdx.x;
  int rp = blk & 31, coT = (blk >> 5) & 1, b = blk >> 6;
  int y0 = rp * 2;
  int coBase = coT * 128;
  int tid = threadIdx.x;
  int w = tid >> 6, lane = tid & 63;
  int wm = w & 1, wn = w >> 1;
  int quad = lane >> 4, l15 = lane & 15;
  int cl = lane & 3;

  __shared__ __align__(16) u16 As[128 * 32];
  __shared__ __align__(16) u16 Bs[128 * 32];

  // staging constants (wave w stages rows [w*32, w*32+32) of each tile; 2 insts of 16 rows)
  const u16* aSrc[2];
  int dstOff[2], chB[2], ylocB[2], xlocB[2];
#pragma unroll
  for (int inst = 0; inst < 2; inst++) {
    int rr = w * 32 + inst * 16 + (lane >> 2);
    int s = (rr ^ (rr >> 2)) & 3;           // XOR swizzle -> 2-way (free) LDS banks
    int ch = cl ^ s;
    aSrc[inst] = wr + (size_t)(b * 256 + coBase + rr) * KK + ch * 8;
    dstOff[inst] = (w * 32 + inst * 16) * 32 + lane * 8;  // = wave-uniform base + lane*16B
    chB[inst] = ch;
    ylocB[inst] = rr >> 6;
    xlocB[inst] = rr & 63;
  }

  // fragment LDS read offsets (fixed across K loop)
  int aOff[4], bOff[4];
#pragma unroll
  for (int i = 0; i < 4; i++) {
    int m = wm * 64 + i * 16 + l15;
    aOff[i] = m * 32 + ((quad ^ ((m ^ (m >> 2)) & 3)) << 3);
    int n = wn * 64 + i * 16 + l15;
    bOff[i] = n * 32 + ((quad ^ ((n ^ (n >> 2)) & 3)) << 3);
  }

  floatx4 acc[4][4];
#pragma unroll
  for (int i = 0; i < 4; i++)
#pragma unroll
    for (int j = 0; j < 4; j++) acc[i][j] = floatx4{0.f, 0.f, 0.f, 0.f};

  for (int kidx = 0; kidx < 9; kidx++) {
    int ky = kidx / 3, kx = kidx - ky * 3;
    const u16* bSrc[2];
#pragma unroll
    for (int inst = 0; inst < 2; inst++) {
      int ys = y0 + ylocB[inst] + ky - 1;
      int xs = xlocB[inst] + kx - 1;
      bool valid = ((unsigned)ys < 64u) && ((unsigned)xs < 64u);
      bSrc[inst] = valid ? (xt + ((size_t)(b * HW_ + ys * 64 + xs) << 7) + chB[inst] * 8)
                         : (zp + chB[inst] * 8);
    }
    const u16* aS0 = aSrc[0] + kidx * 128;
    const u16* aS1 = aSrc[1] + kidx * 128;
#pragma unroll
    for (int cib = 0; cib < 4; cib++) {
      __syncthreads();
      gload_lds16(aS0 + cib * 32, &As[dstOff[0]]);
      gload_lds16(aS1 + cib * 32, &As[dstOff[1]]);
      gload_lds16(bSrc[0] + cib * 32, &Bs[dstOff[0]]);
      gload_lds16(bSrc[1] + cib * 32, &Bs[dstOff[1]]);
      __syncthreads();  // compiler emits s_waitcnt vmcnt(0) before barrier
      bf16x8 af[4], bfv[4];
#pragma unroll
      for (int i = 0; i < 4; i++) af[i] = *(const bf16x8*)&As[aOff[i]];
#pragma unroll
      for (int j = 0; j < 4; j++) bfv[j] = *(const bf16x8*)&Bs[bOff[j]];
#pragma unroll
      for (int i = 0; i < 4; i++)
#pragma unroll
        for (int j = 0; j < 4; j++)
          acc[i][j] = __builtin_amdgcn_mfma_f32_16x16x32_bf16(af[i], bfv[j], acc[i][j], 0, 0, 0);
    }
  }

  // epilogue: out[b][co][y][x] = acc * ca[b][co]
  float cav[4][4];
#pragma unroll
  for (int i = 0; i < 4; i++)
#pragma unroll
    for (int ri = 0; ri < 4; ri++)
      cav[i][ri] = ca[b * 256 + coBase + wm * 64 + i * 16 + quad * 4 + ri];
#pragma unroll
  for (int i = 0; i < 4; i++) {
#pragma unroll
    for (int j = 0; j < 4; j++) {
      int n = wn * 64 + j * 16 + l15;
      int yy = y0 + (n >> 6), xx = n & 63;
#pragma unroll
      for (int ri = 0; ri < 4; ri++) {
        int co = coBase + wm * 64 + i * 16 + quad * 4 + ri;
        out[((size_t)(b * 256 + co) << 12) + (yy << 6) + xx] = acc[i][j][ri] * cav[i][ri];
      }
    }
  }
}

// ---------------- host launch ----------------
extern "C" void kernel_launch(void* const* d_in, const int* in_sizes, int n_in,
                              void* d_out, int out_size, void* d_ws, size_t ws_size,
                              hipStream_t stream) {
  const float* x       = (const float*)d_in[0];
  const float* experts = (const float*)d_in[1];
  const float* rw1 = (const float*)d_in[2];
  const float* rb1 = (const float*)d_in[3];
  const float* rw2 = (const float*)d_in[4];
  const float* rb2 = (const float*)d_in[5];
  const float* rw3 = (const float*)d_in[6];
  const float* rb3 = (const float*)d_in[7];
  const float* aw1 = (const float*)d_in[8];
  const float* ab1 = (const float*)d_in[9];
  const float* aw2 = (const float*)d_in[10];
  const float* ab2 = (const float*)d_in[11];

  // workspace layout (needs ~50.3 MiB)
  char* ws = (char*)d_ws;
  u16*   xt     = (u16*)(ws + 0);              // 33,554,432 B : NHWC bf16
  __hip_bfloat16* wr = (__hip_bfloat16*)(ws + 33554432);  // 18,874,368 B
  float* Sr     = (float*)(ws + 52428800);     // 147,456 B
  float* pooled = (float*)(ws + 52576256);     // 16,384 B
  float* r      = (float*)(ws + 52592640);     // 1,024 B
  float* p      = (float*)(ws + 52593664);     // 32,768 B
  float* ca     = (float*)(ws + 52626432);     // 32,768 B
  u16*   zp     = (u16*)(ws + 52659200);       // 256 B zero page

  k_stats<<<4096, 256, 0, stream>>>(x, Sr, pooled, (unsigned*)zp);
  k_transpose<<<2048, 256, 0, stream>>>(x, xt);
  k_route<<<32, 128, 0, stream>>>(pooled, rw1, rb1, rw2, rb2, rw3, rb3, r);
  k_combine<<<8192, 128, 0, stream>>>(experts, r, wr);
  k_pout<<<8192, 64, 0, stream>>>(wr, Sr, p);
  k_catt<<<32, 256, 0, stream>>>(p, aw1, ab1, aw2, ab2, ca);
  k_conv<<<2048, 256, 0, stream>>>(xt, (const u16*)wr, ca, zp, (float*)d_out);
}

// Round 3
// 332.460 us; speedup vs baseline: 1.0725x; 1.0725x over previous
//
#include <hip/hip_runtime.h>
#include <hip/hip_bf16.h>

// EnhancedCondConv2d: B=32, CI=128, CO=256, H=W=64, E=8, R=16, K=3
// Pipeline (R3: aux overhaul; k_conv byte-identical to R2):
//   k_stats2   : per-(b,ci) plane sums -> pooled, Sr (shifted means), zero page
//   k_xform    : x (NCHW f32) -> xt (NHWC bf16), float4 loads + uint2 stores
//   k_route2   : SE gate -> softmax -> r[b,8]   (16-lane parallel dots)
//   k_combine2 : wr[b][co][k][ci] bf16 AND p[b,co]=w.Sr fused (experts staged in LDS once)
//   k_catt2    : ca[b,co] = sigmoid(relu(p@aw1^T)@aw2^T)  (parallel dots)
//   k_conv     : implicit-GEMM MFMA conv (128x128 tile, 16x16x32 bf16), epilogue *ca

#define BB 32
#define CI_ 128
#define CO_ 256
#define HW_ 4096
#define KK 1152   // CI*9

typedef unsigned short u16;
typedef __attribute__((ext_vector_type(8))) __bf16 bf16x8;
typedef __attribute__((ext_vector_type(4))) float floatx4;

typedef const __attribute__((address_space(1))) void* gptr_t;
typedef __attribute__((address_space(3))) void* sptr_t;

__device__ __forceinline__ void gload_lds16(const void* g, void* s) {
  __builtin_amdgcn_global_load_lds((gptr_t)g, (sptr_t)s, 16, 0, 0);
}

// ---------------- k_stats2: per-(b,ci) plane statistics ----------------
// block = (b,ci) plane; 256 threads, 4 float4 each, fully coalesced.
__global__ __launch_bounds__(256) void k_stats2(const float* __restrict__ x,
                                                float* __restrict__ Sr,
                                                float* __restrict__ pooled,
                                                unsigned* __restrict__ zp) {
  int blk = blockIdx.x;
  int tid = threadIdx.x;
  if (blk == 0 && tid < 64) zp[tid] = 0u;  // 256B zero page
  int b = blk >> 7, ci = blk & 127;
  const float4* xp = (const float4*)(x + ((size_t)(b * CI_ + ci) << 12));
  float T = 0.f, r0 = 0.f, r63 = 0.f, c0 = 0.f, c63 = 0.f;
  __shared__ float corn[4];
  __shared__ float wsum[4][5];
#pragma unroll
  for (int j = 0; j < 4; j++) {
    int idx = j * 256 + tid;          // float4 index in [0,1024); row y = idx>>4, xq = idx&15
    float4 v = xp[idx];
    float rs = v.x + v.y + v.z + v.w;
    T += rs;
    int x16 = idx & 15;
    if (idx < 16)    r0  += rs;       // y == 0
    if (idx >= 1008) r63 += rs;       // y == 63
    if (x16 == 0)  c0  += v.x;        // col 0
    if (x16 == 15) c63 += v.w;        // col 63
    if (idx == 0)    corn[0] = v.x;   // [0][0]
    if (idx == 15)   corn[1] = v.w;   // [0][63]
    if (idx == 1008) corn[2] = v.x;   // [63][0]
    if (idx == 1023) corn[3] = v.w;   // [63][63]
  }
  for (int off = 32; off; off >>= 1) {
    T   += __shfl_down(T, off);
    r0  += __shfl_down(r0, off);
    r63 += __shfl_down(r63, off);
    c0  += __shfl_down(c0, off);
    c63 += __shfl_down(c63, off);
  }
  int w = tid >> 6, lane = tid & 63;
  if (lane == 0) { wsum[w][0]=T; wsum[w][1]=r0; wsum[w][2]=r63; wsum[w][3]=c0; wsum[w][4]=c63; }
  __syncthreads();
  if (tid == 0) {
    T   = wsum[0][0]+wsum[1][0]+wsum[2][0]+wsum[3][0];
    r0  = wsum[0][1]+wsum[1][1]+wsum[2][1]+wsum[3][1];
    r63 = wsum[0][2]+wsum[1][2]+wsum[2][2]+wsum[3][2];
    c0  = wsum[0][3]+wsum[1][3]+wsum[2][3]+wsum[3][3];
    c63 = wsum[0][4]+wsum[1][4]+wsum[2][4]+wsum[3][4];
    pooled[b * CI_ + ci] = T * (1.0f / 4096.0f);
#pragma unroll
    for (int ky = 0; ky < 3; ky++) {
#pragma unroll
      for (int kx = 0; kx < 3; kx++) {
        int dy = ky - 1, dx = kx - 1;
        float s = T;
        if (dy == -1) s -= r63;
        if (dy ==  1) s -= r0;
        if (dx == -1) s -= c63;
        if (dx ==  1) s -= c0;
        if (dy != 0 && dx != 0) s += corn[(dy == -1 ? 2 : 0) + (dx == -1 ? 1 : 0)];
        Sr[(b * 9 + ky * 3 + kx) * CI_ + ci] = s * (1.0f / 4096.0f);
      }
    }
  }
}

// ---------------- k_xform: NCHW f32 -> NHWC bf16 (vectorized) ----------------
__global__ __launch_bounds__(256) void k_xform(const float* __restrict__ x,
                                               u16* __restrict__ xt) {
  int blk = blockIdx.x;          // b*64 + y
  int b = blk >> 6, y = blk & 63;
  __shared__ u16 ts[64][132];
  int tid = threadIdx.x;
  const float* xb = x + ((size_t)b << 19) + (y << 6);
#pragma unroll
  for (int it = 0; it < 8; it++) {
    int idx = it * 256 + tid;        // [0,2048): ci = idx>>4, x4 = idx&15
    int ci = idx >> 4, x4 = idx & 15;
    float4 v = *(const float4*)(xb + (size_t)ci * 4096 + x4 * 4);
    __hip_bfloat16 h0 = __float2bfloat16(v.x), h1 = __float2bfloat16(v.y);
    __hip_bfloat16 h2 = __float2bfloat16(v.z), h3 = __float2bfloat16(v.w);
    int xx = x4 << 2;
    ts[xx + 0][ci] = *(const u16*)&h0;
    ts[xx + 1][ci] = *(const u16*)&h1;
    ts[xx + 2][ci] = *(const u16*)&h2;
    ts[xx + 3][ci] = *(const u16*)&h3;
  }
  __syncthreads();
  uint2* ot = (uint2*)(xt + ((size_t)b * HW_ + y * 64) * CI_);
#pragma unroll
  for (int it = 0; it < 8; it++) {
    int o = it * 256 + tid;          // [0,2048) uint2: pix = o>>5, c4 = o&31
    int pix = o >> 5, c4 = o & 31;
    ot[o] = *(const uint2*)&ts[pix][c4 * 4];
  }
}

// ---------------- k_route2: SE gate -> softmax (parallel dots) ----------------
__global__ __launch_bounds__(128) void k_route2(const float* __restrict__ pooled,
    const float* __restrict__ rw1, const float* __restrict__ rb1,
    const float* __restrict__ rw2, const float* __restrict__ rb2,
    const float* __restrict__ rw3, const float* __restrict__ rb3,
    float* __restrict__ r) {
  int b = blockIdx.x, tid = threadIdx.x;
  int o = tid >> 4, l = tid & 15;
  __shared__ float ps[128], hs[8], ss[128], lg[8];
  ps[tid] = pooled[b * 128 + tid];
  __syncthreads();
  {  // layer 1: 8 outputs, 16 lanes each over 8 elements
    float a = 0.f;
#pragma unroll
    for (int j = 0; j < 8; j++) a += ps[l * 8 + j] * rw1[o * 128 + l * 8 + j];
    a += __shfl_xor(a, 1); a += __shfl_xor(a, 2);
    a += __shfl_xor(a, 4); a += __shfl_xor(a, 8);
    if (l == 0) hs[o] = fmaxf(a + rb1[o], 0.f);
  }
  __syncthreads();
  {  // layer 2: 128 outputs, 8 elements each
    float a = rb2[tid];
#pragma unroll
    for (int j = 0; j < 8; j++) a += hs[j] * rw2[tid * 8 + j];
    ss[tid] = 1.f / (1.f + expf(-a));
  }
  __syncthreads();
  {  // layer 3: 8 logits
    float a = 0.f;
#pragma unroll
    for (int j = 0; j < 8; j++) a += ss[l * 8 + j] * rw3[o * 128 + l * 8 + j];
    a += __shfl_xor(a, 1); a += __shfl_xor(a, 2);
    a += __shfl_xor(a, 4); a += __shfl_xor(a, 8);
    if (l == 0) lg[o] = a + rb3[o];
  }
  __syncthreads();
  if (tid == 0) {
    float m = lg[0];
    for (int e = 1; e < 8; e++) m = fmaxf(m, lg[e]);
    float s = 0.f, ex[8];
    for (int e = 0; e < 8; e++) { ex[e] = expf(lg[e] - m); s += ex[e]; }
    for (int e = 0; e < 8; e++) r[b * 8 + e] = ex[e] / s;
  }
}

// ---------------- k_combine2: wr bf16 + fused pooled-output p ----------------
// block = co (256 blocks), 256 threads = 2 b-slices of 128 ci.
// Experts slab for this co (8 x 1152 f32 = 36 KB) staged in LDS once -> experts
// read exactly once across the grid (9.4 MB total, vs ~295 MB logical in R2).
__global__ __launch_bounds__(256) void k_combine2(const float* __restrict__ experts,
                                                  const float* __restrict__ r,
                                                  const float* __restrict__ Sr,
                                                  __hip_bfloat16* __restrict__ wr,
                                                  float* __restrict__ p) {
  int co = blockIdx.x, tid = threadIdx.x;
  __shared__ float els[8][1152];   // 36864 B
  __shared__ float rsh[32][8];
  __shared__ float pw[4];
#pragma unroll
  for (int it = 0; it < 9; it++) {
    int f = it * 256 + tid;        // [0,2304) float4s
    int e = f / 288, q = f - e * 288;
    float4 ev = *(const float4*)(experts + (size_t)e * 294912 + (size_t)co * 1152 + q * 4);
    *(float4*)&els[e][q * 4] = ev;
  }
  rsh[tid >> 3][tid & 7] = r[tid];
  __syncthreads();
  int s = tid >> 7, ci = tid & 127;
  for (int bb = 0; bb < 16; bb++) {
    int b = bb * 2 + s;
    float rv[8];
#pragma unroll
    for (int e = 0; e < 8; e++) rv[e] = rsh[b][e];
    float pacc = 0.f;
    __hip_bfloat16* wrow = wr + (size_t)(b * 256 + co) * KK;
    const float* sb = Sr + b * KK;
#pragma unroll
    for (int k = 0; k < 9; k++) {
      float v = 0.f;
#pragma unroll
      for (int e = 0; e < 8; e++) v += rv[e] * els[e][ci * 9 + k];
      wrow[k * 128 + ci] = __float2bfloat16(v);
      pacc += v * sb[k * 128 + ci];
    }
    for (int off = 32; off; off >>= 1) pacc += __shfl_down(pacc, off);
    if ((tid & 63) == 0) pw[tid >> 6] = pacc;
    __syncthreads();
    if (ci == 0) p[b * 256 + co] = pw[s * 2] + pw[s * 2 + 1];
    __syncthreads();
  }
}

// ---------------- k_catt2: channel attention (parallel dots) ----------------
__global__ __launch_bounds__(256) void k_catt2(const float* __restrict__ p,
    const float* __restrict__ aw1, const float* __restrict__ ab1,
    const float* __restrict__ aw2, const float* __restrict__ ab2,
    float* __restrict__ ca) {
  int b = blockIdx.x, tid = threadIdx.x;
  int o = tid >> 4, l = tid & 15;
  __shared__ float ps[256], ts[16];
  ps[tid] = p[b * 256 + tid];
  __syncthreads();
  {  // 16 outputs, 16 lanes each over 16 elements
    float a = 0.f;
#pragma unroll
    for (int j = 0; j < 16; j++) a += ps[l * 16 + j] * aw1[o * 256 + l * 16 + j];
    a += __shfl_xor(a, 1); a += __shfl_xor(a, 2);
    a += __shfl_xor(a, 4); a += __shfl_xor(a, 8);
    if (l == 0) ts[o] = fmaxf(a + ab1[o], 0.f);
  }
  __syncthreads();
  float a = ab2[tid];
#pragma unroll
  for (int j = 0; j < 16; j++) a += ts[j] * aw2[tid * 16 + j];
  ca[b * 256 + tid] = 1.f / (1.f + expf(-a));
}

// ---------------- k_conv: implicit-GEMM MFMA conv + ca epilogue ----------------
// (byte-identical to R2)
__global__ __launch_bounds__(256) void k_conv(const u16* __restrict__ xt,
                                              const u16* __restrict__ wr,
                                              const float* __restrict__ ca,
                                              const u16* __restrict__ zp,
                                              float* __restrict__ out) {
  int blk = blockIdx.x;
  int rp = blk & 31, coT = (blk >> 5) & 1, b = blk >> 6;
  int y0 = rp * 2;
  int coBase = coT * 128;
  int tid = threadIdx.x;
  int w = tid >> 6, lane = tid & 63;
  int wm = w & 1, wn = w >> 1;
  int quad = lane >> 4, l15 = lane & 15;
  int cl = lane & 3;

  __shared__ __align__(16) u16 As[128 * 32];
  __shared__ __align__(16) u16 Bs[128 * 32];

  const u16* aSrc[2];
  int dstOff[2], chB[2], ylocB[2], xlocB[2];
#pragma unroll
  for (int inst = 0; inst < 2; inst++) {
    int rr = w * 32 + inst * 16 + (lane >> 2);
    int s = (rr ^ (rr >> 2)) & 3;           // XOR swizzle -> 2-way (free) LDS banks
    int ch = cl ^ s;
    aSrc[inst] = wr + (size_t)(b * 256 + coBase + rr) * KK + ch * 8;
    dstOff[inst] = (w * 32 + inst * 16) * 32 + lane * 8;
    chB[inst] = ch;
    ylocB[inst] = rr >> 6;
    xlocB[inst] = rr & 63;
  }

  int aOff[4], bOff[4];
#pragma unroll
  for (int i = 0; i < 4; i++) {
    int m = wm * 64 + i * 16 + l15;
    aOff[i] = m * 32 + ((quad ^ ((m ^ (m >> 2)) & 3)) << 3);
    int n = wn * 64 + i * 16 + l15;
    bOff[i] = n * 32 + ((quad ^ ((n ^ (n >> 2)) & 3)) << 3);
  }

  floatx4 acc[4][4];
#pragma unroll
  for (int i = 0; i < 4; i++)
#pragma unroll
    for (int j = 0; j < 4; j++) acc[i][j] = floatx4{0.f, 0.f, 0.f, 0.f};

  for (int kidx = 0; kidx < 9; kidx++) {
    int ky = kidx / 3, kx = kidx - ky * 3;
    const u16* bSrc[2];
#pragma unroll
    for (int inst = 0; inst < 2; inst++) {
      int ys = y0 + ylocB[inst] + ky - 1;
      int xs = xlocB[inst] + kx - 1;
      bool valid = ((unsigned)ys < 64u) && ((unsigned)xs < 64u);
      bSrc[inst] = valid ? (xt + ((size_t)(b * HW_ + ys * 64 + xs) << 7) + chB[inst] * 8)
                         : (zp + chB[inst] * 8);
    }
    const u16* aS0 = aSrc[0] + kidx * 128;
    const u16* aS1 = aSrc[1] + kidx * 128;
#pragma unroll
    for (int cib = 0; cib < 4; cib++) {
      __syncthreads();
      gload_lds16(aS0 + cib * 32, &As[dstOff[0]]);
      gload_lds16(aS1 + cib * 32, &As[dstOff[1]]);
      gload_lds16(bSrc[0] + cib * 32, &Bs[dstOff[0]]);
      gload_lds16(bSrc[1] + cib * 32, &Bs[dstOff[1]]);
      __syncthreads();
      bf16x8 af[4], bfv[4];
#pragma unroll
      for (int i = 0; i < 4; i++) af[i] = *(const bf16x8*)&As[aOff[i]];
#pragma unroll
      for (int j = 0; j < 4; j++) bfv[j] = *(const bf16x8*)&Bs[bOff[j]];
#pragma unroll
      for (int i = 0; i < 4; i++)
#pragma unroll
        for (int j = 0; j < 4; j++)
          acc[i][j] = __builtin_amdgcn_mfma_f32_16x16x32_bf16(af[i], bfv[j], acc[i][j], 0, 0, 0);
    }
  }

  float cav[4][4];
#pragma unroll
  for (int i = 0; i < 4; i++)
#pragma unroll
    for (int ri = 0; ri < 4; ri++)
      cav[i][ri] = ca[b * 256 + coBase + wm * 64 + i * 16 + quad * 4 + ri];
#pragma unroll
  for (int i = 0; i < 4; i++) {
#pragma unroll
    for (int j = 0; j < 4; j++) {
      int n = wn * 64 + j * 16 + l15;
      int yy = y0 + (n >> 6), xx = n & 63;
#pragma unroll
      for (int ri = 0; ri < 4; ri++) {
        int co = coBase + wm * 64 + i * 16 + quad * 4 + ri;
        out[((size_t)(b * 256 + co) << 12) + (yy << 6) + xx] = acc[i][j][ri] * cav[i][ri];
      }
    }
  }
}

// ---------------- host launch ----------------
extern "C" void kernel_launch(void* const* d_in, const int* in_sizes, int n_in,
                              void* d_out, int out_size, void* d_ws, size_t ws_size,
                              hipStream_t stream) {
  const float* x       = (const float*)d_in[0];
  const float* experts = (const float*)d_in[1];
  const float* rw1 = (const float*)d_in[2];
  const float* rb1 = (const float*)d_in[3];
  const float* rw2 = (const float*)d_in[4];
  const float* rb2 = (const float*)d_in[5];
  const float* rw3 = (const float*)d_in[6];
  const float* rb3 = (const float*)d_in[7];
  const float* aw1 = (const float*)d_in[8];
  const float* ab1 = (const float*)d_in[9];
  const float* aw2 = (const float*)d_in[10];
  const float* ab2 = (const float*)d_in[11];

  // workspace layout (identical to R2's proven layout, ~50.2 MiB)
  char* ws = (char*)d_ws;
  u16*   xt     = (u16*)(ws + 0);              // 33,554,432 B : NHWC bf16
  __hip_bfloat16* wr = (__hip_bfloat16*)(ws + 33554432);  // 18,874,368 B
  float* Sr     = (float*)(ws + 52428800);     // 147,456 B
  float* pooled = (float*)(ws + 52576256);     // 16,384 B
  float* r      = (float*)(ws + 52592640);     // 1,024 B
  float* p      = (float*)(ws + 52593664);     // 32,768 B
  float* ca     = (float*)(ws + 52626432);     // 32,768 B
  u16*   zp     = (u16*)(ws + 52659200);       // 256 B zero page

  k_stats2<<<4096, 256, 0, stream>>>(x, Sr, pooled, (unsigned*)zp);
  k_xform<<<2048, 256, 0, stream>>>(x, xt);
  k_route2<<<32, 128, 0, stream>>>(pooled, rw1, rb1, rw2, rb2, rw3, rb3, r);
  k_combine2<<<256, 256, 0, stream>>>(experts, r, Sr, wr, p);
  k_catt2<<<32, 256, 0, stream>>>(p, aw1, ab1, aw2, ab2, ca);
  k_conv<<<2048, 256, 0, stream>>>(xt, (const u16*)wr, ca, zp, (float*)d_out);
}

// Round 4
// 309.354 us; speedup vs baseline: 1.1526x; 1.0747x over previous
//
#include <hip/hip_runtime.h>
#include <hip/hip_bf16.h>

// EnhancedCondConv2d: B=32, CI=128, CO=256, H=W=64, E=8, R=16, K=3
// R4: k_conv -> BK=64 (half the barriers), 3-bit XOR LDS swizzle, XCD-aware
//     block swizzle; k_combine2 grid x4. Other kernels identical to R3.

#define BB 32
#define CI_ 128
#define CO_ 256
#define HW_ 4096
#define KK 1152   // CI*9

typedef unsigned short u16;
typedef __attribute__((ext_vector_type(8))) __bf16 bf16x8;
typedef __attribute__((ext_vector_type(4))) float floatx4;

typedef const __attribute__((address_space(1))) void* gptr_t;
typedef __attribute__((address_space(3))) void* sptr_t;

__device__ __forceinline__ void gload_lds16(const void* g, void* s) {
  __builtin_amdgcn_global_load_lds((gptr_t)g, (sptr_t)s, 16, 0, 0);
}

// ---------------- k_stats2: per-(b,ci) plane statistics ----------------
__global__ __launch_bounds__(256) void k_stats2(const float* __restrict__ x,
                                                float* __restrict__ Sr,
                                                float* __restrict__ pooled,
                                                unsigned* __restrict__ zp) {
  int blk = blockIdx.x;
  int tid = threadIdx.x;
  if (blk == 0 && tid < 64) zp[tid] = 0u;  // 256B zero page
  int b = blk >> 7, ci = blk & 127;
  const float4* xp = (const float4*)(x + ((size_t)(b * CI_ + ci) << 12));
  float T = 0.f, r0 = 0.f, r63 = 0.f, c0 = 0.f, c63 = 0.f;
  __shared__ float corn[4];
  __shared__ float wsum[4][5];
#pragma unroll
  for (int j = 0; j < 4; j++) {
    int idx = j * 256 + tid;
    float4 v = xp[idx];
    float rs = v.x + v.y + v.z + v.w;
    T += rs;
    int x16 = idx & 15;
    if (idx < 16)    r0  += rs;
    if (idx >= 1008) r63 += rs;
    if (x16 == 0)  c0  += v.x;
    if (x16 == 15) c63 += v.w;
    if (idx == 0)    corn[0] = v.x;
    if (idx == 15)   corn[1] = v.w;
    if (idx == 1008) corn[2] = v.x;
    if (idx == 1023) corn[3] = v.w;
  }
  for (int off = 32; off; off >>= 1) {
    T   += __shfl_down(T, off);
    r0  += __shfl_down(r0, off);
    r63 += __shfl_down(r63, off);
    c0  += __shfl_down(c0, off);
    c63 += __shfl_down(c63, off);
  }
  int w = tid >> 6, lane = tid & 63;
  if (lane == 0) { wsum[w][0]=T; wsum[w][1]=r0; wsum[w][2]=r63; wsum[w][3]=c0; wsum[w][4]=c63; }
  __syncthreads();
  if (tid == 0) {
    T   = wsum[0][0]+wsum[1][0]+wsum[2][0]+wsum[3][0];
    r0  = wsum[0][1]+wsum[1][1]+wsum[2][1]+wsum[3][1];
    r63 = wsum[0][2]+wsum[1][2]+wsum[2][2]+wsum[3][2];
    c0  = wsum[0][3]+wsum[1][3]+wsum[2][3]+wsum[3][3];
    c63 = wsum[0][4]+wsum[1][4]+wsum[2][4]+wsum[3][4];
    pooled[b * CI_ + ci] = T * (1.0f / 4096.0f);
#pragma unroll
    for (int ky = 0; ky < 3; ky++) {
#pragma unroll
      for (int kx = 0; kx < 3; kx++) {
        int dy = ky - 1, dx = kx - 1;
        float s = T;
        if (dy == -1) s -= r63;
        if (dy ==  1) s -= r0;
        if (dx == -1) s -= c63;
        if (dx ==  1) s -= c0;
        if (dy != 0 && dx != 0) s += corn[(dy == -1 ? 2 : 0) + (dx == -1 ? 1 : 0)];
        Sr[(b * 9 + ky * 3 + kx) * CI_ + ci] = s * (1.0f / 4096.0f);
      }
    }
  }
}

// ---------------- k_xform: NCHW f32 -> NHWC bf16 (vectorized) ----------------
__global__ __launch_bounds__(256) void k_xform(const float* __restrict__ x,
                                               u16* __restrict__ xt) {
  int blk = blockIdx.x;          // b*64 + y
  int b = blk >> 6, y = blk & 63;
  __shared__ u16 ts[64][132];
  int tid = threadIdx.x;
  const float* xb = x + ((size_t)b << 19) + (y << 6);
#pragma unroll
  for (int it = 0; it < 8; it++) {
    int idx = it * 256 + tid;
    int ci = idx >> 4, x4 = idx & 15;
    float4 v = *(const float4*)(xb + (size_t)ci * 4096 + x4 * 4);
    __hip_bfloat16 h0 = __float2bfloat16(v.x), h1 = __float2bfloat16(v.y);
    __hip_bfloat16 h2 = __float2bfloat16(v.z), h3 = __float2bfloat16(v.w);
    int xx = x4 << 2;
    ts[xx + 0][ci] = *(const u16*)&h0;
    ts[xx + 1][ci] = *(const u16*)&h1;
    ts[xx + 2][ci] = *(const u16*)&h2;
    ts[xx + 3][ci] = *(const u16*)&h3;
  }
  __syncthreads();
  uint2* ot = (uint2*)(xt + ((size_t)b * HW_ + y * 64) * CI_);
#pragma unroll
  for (int it = 0; it < 8; it++) {
    int o = it * 256 + tid;
    int pix = o >> 5, c4 = o & 31;
    ot[o] = *(const uint2*)&ts[pix][c4 * 4];
  }
}

// ---------------- k_route2: SE gate -> softmax (parallel dots) ----------------
__global__ __launch_bounds__(128) void k_route2(const float* __restrict__ pooled,
    const float* __restrict__ rw1, const float* __restrict__ rb1,
    const float* __restrict__ rw2, const float* __restrict__ rb2,
    const float* __restrict__ rw3, const float* __restrict__ rb3,
    float* __restrict__ r) {
  int b = blockIdx.x, tid = threadIdx.x;
  int o = tid >> 4, l = tid & 15;
  __shared__ float ps[128], hs[8], ss[128], lg[8];
  ps[tid] = pooled[b * 128 + tid];
  __syncthreads();
  {
    float a = 0.f;
#pragma unroll
    for (int j = 0; j < 8; j++) a += ps[l * 8 + j] * rw1[o * 128 + l * 8 + j];
    a += __shfl_xor(a, 1); a += __shfl_xor(a, 2);
    a += __shfl_xor(a, 4); a += __shfl_xor(a, 8);
    if (l == 0) hs[o] = fmaxf(a + rb1[o], 0.f);
  }
  __syncthreads();
  {
    float a = rb2[tid];
#pragma unroll
    for (int j = 0; j < 8; j++) a += hs[j] * rw2[tid * 8 + j];
    ss[tid] = 1.f / (1.f + expf(-a));
  }
  __syncthreads();
  {
    float a = 0.f;
#pragma unroll
    for (int j = 0; j < 8; j++) a += ss[l * 8 + j] * rw3[o * 128 + l * 8 + j];
    a += __shfl_xor(a, 1); a += __shfl_xor(a, 2);
    a += __shfl_xor(a, 4); a += __shfl_xor(a, 8);
    if (l == 0) lg[o] = a + rb3[o];
  }
  __syncthreads();
  if (tid == 0) {
    float m = lg[0];
    for (int e = 1; e < 8; e++) m = fmaxf(m, lg[e]);
    float s = 0.f, ex[8];
    for (int e = 0; e < 8; e++) { ex[e] = expf(lg[e] - m); s += ex[e]; }
    for (int e = 0; e < 8; e++) r[b * 8 + e] = ex[e] / s;
  }
}

// ---------------- k_combine2: wr bf16 + fused pooled-output p ----------------
// grid = 1024: co (256) x b-group (4); each block handles 8 b (4 iters x 2 slices).
__global__ __launch_bounds__(256) void k_combine2(const float* __restrict__ experts,
                                                  const float* __restrict__ r,
                                                  const float* __restrict__ Sr,
                                                  __hip_bfloat16* __restrict__ wr,
                                                  float* __restrict__ p) {
  int co = blockIdx.x & 255, g = blockIdx.x >> 8;
  int tid = threadIdx.x;
  __shared__ float els[8][1152];   // 36864 B
  __shared__ float rsh[32][8];
  __shared__ float pw[4];
#pragma unroll
  for (int it = 0; it < 9; it++) {
    int f = it * 256 + tid;        // [0,2304) float4s
    int e = f / 288, q = f - e * 288;
    float4 ev = *(const float4*)(experts + (size_t)e * 294912 + (size_t)co * 1152 + q * 4);
    *(float4*)&els[e][q * 4] = ev;
  }
  rsh[tid >> 3][tid & 7] = r[tid];
  __syncthreads();
  int s = tid >> 7, ci = tid & 127;
  for (int bb = 0; bb < 4; bb++) {
    int b = g * 8 + bb * 2 + s;
    float rv[8];
#pragma unroll
    for (int e = 0; e < 8; e++) rv[e] = rsh[b][e];
    float pacc = 0.f;
    __hip_bfloat16* wrow = wr + (size_t)(b * 256 + co) * KK;
    const float* sb = Sr + b * KK;
#pragma unroll
    for (int k = 0; k < 9; k++) {
      float v = 0.f;
#pragma unroll
      for (int e = 0; e < 8; e++) v += rv[e] * els[e][ci * 9 + k];
      wrow[k * 128 + ci] = __float2bfloat16(v);
      pacc += v * sb[k * 128 + ci];
    }
    for (int off = 32; off; off >>= 1) pacc += __shfl_down(pacc, off);
    if ((tid & 63) == 0) pw[tid >> 6] = pacc;
    __syncthreads();
    if (ci == 0) p[b * 256 + co] = pw[s * 2] + pw[s * 2 + 1];
    __syncthreads();
  }
}

// ---------------- k_catt2: channel attention (parallel dots) ----------------
__global__ __launch_bounds__(256) void k_catt2(const float* __restrict__ p,
    const float* __restrict__ aw1, const float* __restrict__ ab1,
    const float* __restrict__ aw2, const float* __restrict__ ab2,
    float* __restrict__ ca) {
  int b = blockIdx.x, tid = threadIdx.x;
  int o = tid >> 4, l = tid & 15;
  __shared__ float ps[256], ts[16];
  ps[tid] = p[b * 256 + tid];
  __syncthreads();
  {
    float a = 0.f;
#pragma unroll
    for (int j = 0; j < 16; j++) a += ps[l * 16 + j] * aw1[o * 256 + l * 16 + j];
    a += __shfl_xor(a, 1); a += __shfl_xor(a, 2);
    a += __shfl_xor(a, 4); a += __shfl_xor(a, 8);
    if (l == 0) ts[o] = fmaxf(a + ab1[o], 0.f);
  }
  __syncthreads();
  float a = ab2[tid];
#pragma unroll
  for (int j = 0; j < 16; j++) a += ts[j] * aw2[tid * 16 + j];
  ca[b * 256 + tid] = 1.f / (1.f + expf(-a));
}

// ---------------- k_conv: implicit-GEMM MFMA conv, BK=64 ----------------
// grid = 2048, XCD-swizzled: b = (id&7) + 8*((id>>9)&3) so each XCD owns 4 b.
// Block tile: M=128 co, N=128 pos (2 rows), K-loop: 9 kidx x 2 ci-halves of 64.
// LDS: As/Bs 128 rows x 64 u16 (128 B pitch), chunk swizzle p = c ^ (row&7).
__global__ __launch_bounds__(256) void k_conv(const u16* __restrict__ xt,
                                              const u16* __restrict__ wr,
                                              const float* __restrict__ ca,
                                              const u16* __restrict__ zp,
                                              float* __restrict__ out) {
  int id = blockIdx.x;
  int b = (id & 7) | (((id >> 9) & 3) << 3);
  int rem = (id >> 3) & 63;
  int coT = rem >> 5, rp = rem & 31;
  int y0 = rp * 2;
  int coBase = coT * 128;
  int tid = threadIdx.x;
  int w = tid >> 6, lane = tid & 63;
  int wm = w & 1, wn = w >> 1;
  int quad = lane >> 4, l15 = lane & 15;
  int cl8 = lane & 7, lr = lane >> 3;

  __shared__ __align__(16) u16 As[128 * 64];   // 16 KB
  __shared__ __align__(16) u16 Bs[128 * 64];   // 16 KB

  // staging: 4 rounds; round ri stages rows [ri*32 + w*8 + lr], chunk pos cl8.
  const u16* aP[4];
  int dstO[4], chB[4], ylocB[4], xlocB[4];
#pragma unroll
  for (int ri = 0; ri < 4; ri++) {
    int rr = ri * 32 + w * 8 + lr;
    int c = cl8 ^ (rr & 7);                 // source k-chunk for LDS position cl8
    aP[ri] = wr + (size_t)(b * 256 + coBase + rr) * KK + c * 8;
    dstO[ri] = rr * 64 + cl8 * 8;           // = wave-uniform base + lane*16B
    chB[ri] = c;
    ylocB[ri] = rr >> 6;
    xlocB[ri] = rr & 63;
  }

  // fragment LDS read offsets: position = (h*4+quad) ^ (m&7)
  int aOff[4][2], bOff[4][2];
#pragma unroll
  for (int i = 0; i < 4; i++) {
    int m = wm * 64 + i * 16 + l15;
    int n = wn * 64 + i * 16 + l15;
#pragma unroll
    for (int h = 0; h < 2; h++) {
      aOff[i][h] = m * 64 + ((((h << 2) | quad) ^ (m & 7)) << 3);
      bOff[i][h] = n * 64 + ((((h << 2) | quad) ^ (n & 7)) << 3);
    }
  }

  floatx4 acc[4][4];
#pragma unroll
  for (int i = 0; i < 4; i++)
#pragma unroll
    for (int j = 0; j < 4; j++) acc[i][j] = floatx4{0.f, 0.f, 0.f, 0.f};

  for (int kidx = 0; kidx < 9; kidx++) {
    int ky = kidx / 3, kx = kidx - ky * 3;
    const u16* bP[4];
    int bStep[4];
#pragma unroll
    for (int ri = 0; ri < 4; ri++) {
      int ys = y0 + ylocB[ri] + ky - 1;
      int xs = xlocB[ri] + kx - 1;
      bool valid = ((unsigned)ys < 64u) && ((unsigned)xs < 64u);
      bP[ri] = valid ? (xt + ((size_t)(b * HW_ + ys * 64 + xs) << 7) + chB[ri] * 8)
                     : (zp + chB[ri] * 8);
      bStep[ri] = valid ? 64 : 0;
    }
#pragma unroll
    for (int cib = 0; cib < 2; cib++) {
      __syncthreads();
#pragma unroll
      for (int ri = 0; ri < 4; ri++)
        gload_lds16(aP[ri] + kidx * 128 + cib * 64, &As[dstO[ri]]);
#pragma unroll
      for (int ri = 0; ri < 4; ri++)
        gload_lds16(bP[ri] + cib * bStep[ri], &Bs[dstO[ri]]);
      __syncthreads();
#pragma unroll
      for (int h = 0; h < 2; h++) {
        bf16x8 af[4], bfv[4];
#pragma unroll
        for (int i = 0; i < 4; i++) af[i] = *(const bf16x8*)&As[aOff[i][h]];
#pragma unroll
        for (int j = 0; j < 4; j++) bfv[j] = *(const bf16x8*)&Bs[bOff[j][h]];
#pragma unroll
        for (int i = 0; i < 4; i++)
#pragma unroll
          for (int j = 0; j < 4; j++)
            acc[i][j] = __builtin_amdgcn_mfma_f32_16x16x32_bf16(af[i], bfv[j], acc[i][j], 0, 0, 0);
      }
    }
  }

  // epilogue: out[b][co][y][x] = acc * ca[b][co]
  float cav[4][4];
#pragma unroll
  for (int i = 0; i < 4; i++)
#pragma unroll
    for (int ri = 0; ri < 4; ri++)
      cav[i][ri] = ca[b * 256 + coBase + wm * 64 + i * 16 + quad * 4 + ri];
#pragma unroll
  for (int i = 0; i < 4; i++) {
#pragma unroll
    for (int j = 0; j < 4; j++) {
      int n = wn * 64 + j * 16 + l15;
      int yy = y0 + (n >> 6), xx = n & 63;
#pragma unroll
      for (int ri = 0; ri < 4; ri++) {
        int co = coBase + wm * 64 + i * 16 + quad * 4 + ri;
        out[((size_t)(b * 256 + co) << 12) + (yy << 6) + xx] = acc[i][j][ri] * cav[i][ri];
      }
    }
  }
}

// ---------------- host launch ----------------
extern "C" void kernel_launch(void* const* d_in, const int* in_sizes, int n_in,
                              void* d_out, int out_size, void* d_ws, size_t ws_size,
                              hipStream_t stream) {
  const float* x       = (const float*)d_in[0];
  const float* experts = (const float*)d_in[1];
  const float* rw1 = (const float*)d_in[2];
  const float* rb1 = (const float*)d_in[3];
  const float* rw2 = (const float*)d_in[4];
  const float* rb2 = (const float*)d_in[5];
  const float* rw3 = (const float*)d_in[6];
  const float* rb3 = (const float*)d_in[7];
  const float* aw1 = (const float*)d_in[8];
  const float* ab1 = (const float*)d_in[9];
  const float* aw2 = (const float*)d_in[10];
  const float* ab2 = (const float*)d_in[11];

  char* ws = (char*)d_ws;
  u16*   xt     = (u16*)(ws + 0);              // 33,554,432 B : NHWC bf16
  __hip_bfloat16* wr = (__hip_bfloat16*)(ws + 33554432);  // 18,874,368 B
  float* Sr     = (float*)(ws + 52428800);     // 147,456 B
  float* pooled = (float*)(ws + 52576256);     // 16,384 B
  float* r      = (float*)(ws + 52592640);     // 1,024 B
  float* p      = (float*)(ws + 52593664);     // 32,768 B
  float* ca     = (float*)(ws + 52626432);     // 32,768 B
  u16*   zp     = (u16*)(ws + 52659200);       // 256 B zero page

  k_stats2<<<4096, 256, 0, stream>>>(x, Sr, pooled, (unsigned*)zp);
  k_xform<<<2048, 256, 0, stream>>>(x, xt);
  k_route2<<<32, 128, 0, stream>>>(pooled, rw1, rb1, rw2, rb2, rw3, rb3, r);
  k_combine2<<<1024, 256, 0, stream>>>(experts, r, Sr, wr, p);
  k_catt2<<<32, 256, 0, stream>>>(p, aw1, ab1, aw2, ab2, ca);
  k_conv<<<2048, 256, 0, stream>>>(xt, (const u16*)wr, ca, zp, (float*)d_out);
}